// Round 1
// baseline (584.079 us; speedup 1.0000x reference)
//
#include <hip/hip_runtime.h>
#include <cmath>

#define IGNORE_INDEX (-100)
#define SMOOTHING 0.2f

__device__ __forceinline__ float wave_reduce_max(float v) {
#pragma unroll
    for (int off = 32; off > 0; off >>= 1)
        v = fmaxf(v, __shfl_xor(v, off, 64));
    return v;
}
__device__ __forceinline__ float wave_reduce_sum(float v) {
#pragma unroll
    for (int off = 32; off > 0; off >>= 1)
        v += __shfl_xor(v, off, 64);
    return v;
}

// Kernel A: per-class soft row S[c][j] = 0.8*d(j==c) + 0.2*sim[c][j]/rowsum,
// and per-class entropy H[c] = sum_j S*log(S). One wave per class.
// Also zero-inits the accumulator and the completion ticket (stream-ordered
// before main; re-runs on every graph replay).
__global__ void prep_kernel(const float* __restrict__ sim, float* __restrict__ S,
                            float* __restrict__ H, float* __restrict__ acc,
                            unsigned* __restrict__ ticket, int C) {
    const int c = blockIdx.x;
    const int lane = threadIdx.x;  // blockDim.x == 64
    if (c == 0 && lane == 0) {
        acc[0] = 0.f;
        ticket[0] = 0u;
    }

    float psum = 0.f;
    for (int j = lane; j < C; j += 64) psum += sim[(size_t)c * C + j];
    const float inv = 1.f / wave_reduce_sum(psum);

    float h = 0.f;
    for (int j = lane; j < C; j += 64) {
        float s = SMOOTHING * sim[(size_t)c * C + j] * inv + ((j == c) ? (1.f - SMOOTHING) : 0.f);
        S[(size_t)c * C + j] = s;
        if (s > 0.f) h += s * logf(s);
    }
    h = wave_reduce_sum(h);
    if (lane == 0) H[c] = h;
}

// Shared epilogue: per-block atomicAdd into acc, then the LAST block to
// finish (device-scope ticket) publishes out = max(acc/B, 0). The final
// read uses atomicAdd(acc, 0.f) so it is served at the device-coherent
// point (per-XCD L2s are not cross-coherent for plain loads).
__device__ __forceinline__ void block_epilogue(float blocksum, float* acc,
                                               unsigned* ticket, float* out,
                                               float invB) {
    if (threadIdx.x == 0) {
        atomicAdd(acc, blocksum);
        __threadfence();                         // release acc-add before ticket
        unsigned old = atomicAdd(ticket, 1u);
        if (old == (unsigned)(gridDim.x - 1)) {
            float tot = atomicAdd(acc, 0.f);     // coherent read of final sum
            out[0] = fmaxf(tot * invB, 0.f);
        }
    }
}

// Kernel B (C known at compile time): 16 LANES PER SAMPLE.
// The LDS/DS pipe is CU-shared (4 SIMDs -> one LDS unit), so shuffle chains
// dominate: v2 spent 12 DS ops/sample = ~60us/CU on the LDS pipe alone.
// Here lanes split into 4 groups of 16; xor-shuffle offsets 8,4,2,1 reduce
// all FOUR samples in one 4-step chain -> 2 DS ops/sample (6x fewer).
// kl_i = H[t] - dot(S[t],x_i) + lse_i; dot accumulates per-lane, reduced once.
template <int CC>
__global__ __launch_bounds__(256) void main_kernel_t(
    const float* __restrict__ logits, const int* __restrict__ targets,
    const float* __restrict__ S, const float* __restrict__ H,
    float* __restrict__ acc, unsigned* __restrict__ ticket,
    float* __restrict__ out, float invB, int Bn) {
    constexpr int NF2 = CC / 2;              // float2 per row (85)
    constexpr int NCH = (NF2 + 15) / 16;     // chunks per 16-lane group (6)

    const int lane = threadIdx.x & 63;
    const int wid  = threadIdx.x >> 6;
    const int wave = blockIdx.x * 4 + wid;
    const int nwaves = gridDim.x * 4;
    const int spw = (Bn + nwaves - 1) / nwaves;     // samples per wave (64)
    const int start = wave * spw;
    const int end = (start + spw < Bn) ? (start + spw) : Bn;

    const int g = lane >> 4;    // which of 4 samples this lane serves
    const int u = lane & 15;    // sublane within the 16-lane group

    float dotacc = 0.f;   // per-lane, folded into the single final reduction
    float usum   = 0.f;   // per-lane, only u==0 lanes contribute

    for (int i = start; i < end; i += 4) {
        const int s_idx = i + g;
        const bool in_range = (s_idx < end);
        const int t = in_range ? targets[s_idx] : IGNORE_INDEX;
        const bool v = in_range && (t != IGNORE_INDEX);
        const int cls = v ? t : 0;

        const float2* xr = (const float2*)(logits + (size_t)(in_range ? s_idx : start) * CC);
        const float2* sr = (const float2*)(S + (size_t)cls * CC);

        float2 x[NCH], sv[NCH];
#pragma unroll
        for (int c = 0; c < NCH; ++c) {
            const bool ok = (c * 16 + u < NF2) && in_range;
            x[c]  = ok ? xr[c * 16 + u] : make_float2(-INFINITY, -INFINITY);
            sv[c] = ok ? sr[c * 16 + u] : make_float2(0.f, 0.f);
        }

        // group max: 4-step chain serves all 4 samples at once
        float m = -INFINITY;
#pragma unroll
        for (int c = 0; c < NCH; ++c) m = fmaxf(m, fmaxf(x[c].x, x[c].y));
#pragma unroll
        for (int off = 8; off >= 1; off >>= 1)
            m = fmaxf(m, __shfl_xor(m, off, 64));

        float se = 0.f, d = 0.f;
#pragma unroll
        for (int c = 0; c < NCH; ++c) {
            se += __expf(x[c].x - m) + __expf(x[c].y - m);
            // guard: sentinel slots have sv=0 but x=-INF -> 0*inf = NaN
            const bool ok = (c * 16 + u < NF2) && in_range;
            d += ok ? (sv[c].x * x[c].x + sv[c].y * x[c].y) : 0.f;
        }
#pragma unroll
        for (int off = 8; off >= 1; off >>= 1)
            se += __shfl_xor(se, off, 64);

        dotacc += v ? d : 0.f;
        const float lse = m + __logf(se);
        usum += (v && u == 0) ? (H[cls] + lse) : 0.f;
    }

    float tot = usum - dotacc;
    tot = wave_reduce_sum(tot);   // once per wave, amortized over 64 samples

    __shared__ float wsums[4];
    if (lane == 0) wsums[wid] = tot;
    __syncthreads();
    block_epilogue(wsums[0] + wsums[1] + wsums[2] + wsums[3], acc, ticket, out, invB);
}

// Generic fallback (C != 170): one wave per sample, grid-stride.
__global__ __launch_bounds__(256) void main_kernel_gen(
    const float* __restrict__ logits, const int* __restrict__ targets,
    const float* __restrict__ S, const float* __restrict__ H,
    float* __restrict__ acc, unsigned* __restrict__ ticket,
    float* __restrict__ out, float invB, int Bn, int C) {
    const int lane = threadIdx.x & 63;
    const int wid = threadIdx.x >> 6;
    const int wave = blockIdx.x * 4 + wid;
    const int nwaves = gridDim.x * 4;

    float wsum = 0.f;
    for (int i = wave; i < Bn; i += nwaves) {
        const int t = targets[i];
        const bool v = (t != IGNORE_INDEX);
        const int cls = v ? t : 0;
        const float* xr = logits + (size_t)i * C;
        const float* sr = S + (size_t)cls * C;
        float m = -INFINITY;
        for (int j = lane; j < C; j += 64) m = fmaxf(m, xr[j]);
        m = wave_reduce_max(m);
        float se = 0.f, d = 0.f;
        for (int j = lane; j < C; j += 64) {
            se += __expf(xr[j] - m);
            d += sr[j] * xr[j];
        }
        se = wave_reduce_sum(se);
        d = wave_reduce_sum(d);
        wsum += v ? (H[cls] + m + __logf(se) - d) : 0.f;
    }
    __shared__ float wsums[4];
    if (lane == 0) wsums[wid] = wsum;
    __syncthreads();
    block_epilogue(wsums[0] + wsums[1] + wsums[2] + wsums[3], acc, ticket, out, invB);
}

extern "C" void kernel_launch(void* const* d_in, const int* in_sizes, int n_in,
                              void* d_out, int out_size, void* d_ws, size_t ws_size,
                              hipStream_t stream) {
    const float* logits = (const float*)d_in[0];
    const int* targets = (const int*)d_in[1];
    const float* sim = (const float*)d_in[2];
    float* out = (float*)d_out;

    const int Bn = in_sizes[1];
    const int C = in_sizes[0] / Bn;

    char* ws = (char*)d_ws;
    float* S = (float*)ws;                                   // C*C floats
    float* H = (float*)(ws + (size_t)C * C * sizeof(float)); // C floats
    size_t off = ((size_t)C * C + (size_t)C) * sizeof(float);
    off = (off + 255) & ~(size_t)255;
    float* acc = (float*)(ws + off);                         // 1 float accumulator
    unsigned* ticket = (unsigned*)(ws + off + sizeof(float)); // completion ticket

    prep_kernel<<<C, 64, 0, stream>>>(sim, S, H, acc, ticket, C);

    const float invB = 1.0f / (float)Bn;
    // 2048 blocks x 4 waves = 8192 waves; each wave owns a contiguous
    // 64-sample span, processed 4 samples per iteration (16 lanes each).
    if (C == 170) {
        main_kernel_t<170><<<2048, 256, 0, stream>>>(logits, targets, S, H, acc, ticket, out, invB, Bn);
    } else {
        main_kernel_gen<<<2048, 256, 0, stream>>>(logits, targets, S, H, acc, ticket, out, invB, Bn, C);
    }
}

// Round 3
// 495.716 us; speedup vs baseline: 1.1783x; 1.1783x over previous
//
#include <hip/hip_runtime.h>
#include <cmath>

#define IGNORE_INDEX (-100)
#define SMOOTHING 0.2f

__device__ __forceinline__ float wave_reduce_max(float v) {
#pragma unroll
    for (int off = 32; off > 0; off >>= 1)
        v = fmaxf(v, __shfl_xor(v, off, 64));
    return v;
}
__device__ __forceinline__ float wave_reduce_sum(float v) {
#pragma unroll
    for (int off = 32; off > 0; off >>= 1)
        v += __shfl_xor(v, off, 64);
    return v;
}

// Kernel A: per-class soft row S[c][j] = 0.8*d(j==c) + 0.2*sim[c][j]/rowsum,
// and per-class entropy H[c] = sum_j S*log(S). One wave per class.
__global__ void prep_kernel(const float* __restrict__ sim, float* __restrict__ S,
                            float* __restrict__ H, int C) {
    const int c = blockIdx.x;
    const int lane = threadIdx.x;  // blockDim.x == 64

    float psum = 0.f;
    for (int j = lane; j < C; j += 64) psum += sim[(size_t)c * C + j];
    const float inv = 1.f / wave_reduce_sum(psum);

    float h = 0.f;
    for (int j = lane; j < C; j += 64) {
        float s = SMOOTHING * sim[(size_t)c * C + j] * inv + ((j == c) ? (1.f - SMOOTHING) : 0.f);
        S[(size_t)c * C + j] = s;
        if (s > 0.f) h += s * logf(s);
    }
    h = wave_reduce_sum(h);
    if (lane == 0) H[c] = h;
}

// Kernel B (C known at compile time): 16 LANES PER SAMPLE.
// Lanes split into 4 groups of 16; xor-shuffle offsets 8,4,2,1 reduce
// all FOUR samples in one 4-step chain -> 2 DS ops/sample.
// kl_i = H[t] - dot(S[t],x_i) + lse_i; dot accumulates per-lane, reduced once.
//
// Epilogue: PLAIN STORE of the block partial to partials[blockIdx.x].
// NO same-address atomics: this kernel is perfectly load-balanced and
// memory-bound, so all 2048 blocks finish near-simultaneously; a single
// shared atomic accumulator serializes ~2048 cross-XCD same-line RMWs
// (~50-90 ns each) into a fully EXPOSED ~100-180 us tail (measured:
// +90 us when a second chain + fence was added in a previous round).
// Disjoint plain stores have zero contention; the 1-block finish kernel
// sums them (kernel-boundary stream ordering guarantees visibility).
template <int CC>
__global__ __launch_bounds__(256) void main_kernel_t(
    const float* __restrict__ logits, const int* __restrict__ targets,
    const float* __restrict__ S, const float* __restrict__ H,
    float* __restrict__ partials, int Bn) {
    constexpr int NF2 = CC / 2;              // float2 per row (85)
    constexpr int NCH = (NF2 + 15) / 16;     // chunks per 16-lane group (6)

    const int lane = threadIdx.x & 63;
    const int wid  = threadIdx.x >> 6;
    const int wave = blockIdx.x * 4 + wid;
    const int nwaves = gridDim.x * 4;
    const int spw = (Bn + nwaves - 1) / nwaves;     // samples per wave (64)
    const int start = wave * spw;
    const int end = (start + spw < Bn) ? (start + spw) : Bn;

    const int g = lane >> 4;    // which of 4 samples this lane serves
    const int u = lane & 15;    // sublane within the 16-lane group

    float dotacc = 0.f;   // per-lane, folded into the single final reduction
    float usum   = 0.f;   // per-lane, only u==0 lanes contribute

    for (int i = start; i < end; i += 4) {
        const int s_idx = i + g;
        const bool in_range = (s_idx < end);
        const int t = in_range ? targets[s_idx] : IGNORE_INDEX;
        const bool v = in_range && (t != IGNORE_INDEX);
        const int cls = v ? t : 0;

        const float2* xr = (const float2*)(logits + (size_t)(in_range ? s_idx : start) * CC);
        const float2* sr = (const float2*)(S + (size_t)cls * CC);

        float2 x[NCH], sv[NCH];
#pragma unroll
        for (int c = 0; c < NCH; ++c) {
            const bool ok = (c * 16 + u < NF2) && in_range;
            x[c]  = ok ? xr[c * 16 + u] : make_float2(-INFINITY, -INFINITY);
            sv[c] = ok ? sr[c * 16 + u] : make_float2(0.f, 0.f);
        }

        // group max: 4-step chain serves all 4 samples at once
        float m = -INFINITY;
#pragma unroll
        for (int c = 0; c < NCH; ++c) m = fmaxf(m, fmaxf(x[c].x, x[c].y));
#pragma unroll
        for (int off = 8; off >= 1; off >>= 1)
            m = fmaxf(m, __shfl_xor(m, off, 64));

        float se = 0.f, d = 0.f;
#pragma unroll
        for (int c = 0; c < NCH; ++c) {
            se += __expf(x[c].x - m) + __expf(x[c].y - m);
            // guard: sentinel slots have sv=0 but x=-INF -> 0*inf = NaN
            const bool ok = (c * 16 + u < NF2) && in_range;
            d += ok ? (sv[c].x * x[c].x + sv[c].y * x[c].y) : 0.f;
        }
#pragma unroll
        for (int off = 8; off >= 1; off >>= 1)
            se += __shfl_xor(se, off, 64);

        dotacc += v ? d : 0.f;
        const float lse = m + __logf(se);
        usum += (v && u == 0) ? (H[cls] + lse) : 0.f;
    }

    float tot = usum - dotacc;
    tot = wave_reduce_sum(tot);   // once per wave, amortized over 64 samples

    __shared__ float wsums[4];
    if (lane == 0) wsums[wid] = tot;
    __syncthreads();
    if (threadIdx.x == 0)
        partials[blockIdx.x] = wsums[0] + wsums[1] + wsums[2] + wsums[3];
}

// Generic fallback (C != 170): one wave per sample, grid-stride.
__global__ __launch_bounds__(256) void main_kernel_gen(
    const float* __restrict__ logits, const int* __restrict__ targets,
    const float* __restrict__ S, const float* __restrict__ H,
    float* __restrict__ partials, int Bn, int C) {
    const int lane = threadIdx.x & 63;
    const int wid = threadIdx.x >> 6;
    const int wave = blockIdx.x * 4 + wid;
    const int nwaves = gridDim.x * 4;

    float wsum = 0.f;
    for (int i = wave; i < Bn; i += nwaves) {
        const int t = targets[i];
        const bool v = (t != IGNORE_INDEX);
        const int cls = v ? t : 0;
        const float* xr = logits + (size_t)i * C;
        const float* sr = S + (size_t)cls * C;
        float m = -INFINITY;
        for (int j = lane; j < C; j += 64) m = fmaxf(m, xr[j]);
        m = wave_reduce_max(m);
        float se = 0.f, d = 0.f;
        for (int j = lane; j < C; j += 64) {
            se += __expf(xr[j] - m);
            d += sr[j] * xr[j];
        }
        se = wave_reduce_sum(se);
        d = wave_reduce_sum(d);
        wsum += v ? (H[cls] + m + __logf(se) - d) : 0.f;
    }
    __shared__ float wsums[4];
    if (lane == 0) wsums[wid] = wsum;
    __syncthreads();
    if (threadIdx.x == 0)
        partials[blockIdx.x] = wsums[0] + wsums[1] + wsums[2] + wsums[3];
}

// Kernel C: out = max(sum(partials)/B, 0). One block, 256 threads.
__global__ __launch_bounds__(256) void finish_kernel(const float* __restrict__ partials,
                                                     int np, float* __restrict__ out,
                                                     float invB) {
    const int lane = threadIdx.x & 63;
    const int wid = threadIdx.x >> 6;
    float s = 0.f;
    for (int i = threadIdx.x; i < np; i += 256) s += partials[i];
    s = wave_reduce_sum(s);
    __shared__ float w[4];
    if (lane == 0) w[wid] = s;
    __syncthreads();
    if (threadIdx.x == 0)
        out[0] = fmaxf((w[0] + w[1] + w[2] + w[3]) * invB, 0.f);
}

extern "C" void kernel_launch(void* const* d_in, const int* in_sizes, int n_in,
                              void* d_out, int out_size, void* d_ws, size_t ws_size,
                              hipStream_t stream) {
    const float* logits = (const float*)d_in[0];
    const int* targets = (const int*)d_in[1];
    const float* sim = (const float*)d_in[2];
    float* out = (float*)d_out;

    const int Bn = in_sizes[1];
    const int C = in_sizes[0] / Bn;

    constexpr int NBLK = 2048;

    char* ws = (char*)d_ws;
    float* S = (float*)ws;                                   // C*C floats
    float* H = (float*)(ws + (size_t)C * C * sizeof(float)); // C floats
    size_t off = ((size_t)C * C + (size_t)C) * sizeof(float);
    off = (off + 255) & ~(size_t)255;
    float* partials = (float*)(ws + off);                    // NBLK floats

    prep_kernel<<<C, 64, 0, stream>>>(sim, S, H, C);

    // 2048 blocks x 4 waves = 8192 waves; each wave owns a contiguous
    // 64-sample span, processed 4 samples per iteration (16 lanes each).
    if (C == 170) {
        main_kernel_t<170><<<NBLK, 256, 0, stream>>>(logits, targets, S, H, partials, Bn);
    } else {
        main_kernel_gen<<<NBLK, 256, 0, stream>>>(logits, targets, S, H, partials, Bn, C);
    }

    finish_kernel<<<1, 256, 0, stream>>>(partials, NBLK, out, 1.0f / (float)Bn);
}